// Round 1
// baseline (915.483 us; speedup 1.0000x reference)
//
#include <hip/hip_runtime.h>
#include <hip/hip_bf16.h>
#include <math.h>

#define T_SEQ 2048
#define NH 16
#define C3 3072
#define C_DIM 1024

typedef __bf16 bf16_t;
typedef __bf16 bf16x8 __attribute__((ext_vector_type(8)));
typedef __bf16 bf16x4_t __attribute__((ext_vector_type(4)));
typedef float f32x4 __attribute__((ext_vector_type(4)));

static __device__ __forceinline__ bf16x8 ldfrag(const bf16_t* p) {
    return *reinterpret_cast<const bf16x8*>(p);
}

// f32 -> bf16, 4 elems/thread; first launch also zeroes the 2 energy accumulators
__global__ void cvt4_kernel(const float* __restrict__ in, bf16_t* __restrict__ out,
                            long n4, float* zbuf) {
    long i = (long)blockIdx.x * blockDim.x + threadIdx.x;
    if (zbuf && i < 2) zbuf[i] = 0.f;
    long stride = (long)gridDim.x * blockDim.x;
    for (; i < n4; i += stride) {
        float4 v = ((const float4*)in)[i];
        bf16x4_t o;
        o[0] = (bf16_t)v.x; o[1] = (bf16_t)v.y; o[2] = (bf16_t)v.z; o[3] = (bf16_t)v.w;
        *(bf16x4_t*)(out + i * 4) = o;
    }
}

__global__ void dists_kernel(float* __restrict__ dout) {
    int idx = blockIdx.x * 256 + threadIdx.x;
    int i = idx >> 11, j = idx & 2047;
    dout[idx] = (float)(i > j ? i - j : j - i);
}

// C = A @ B^T, A[M,K], B[N,K] bf16 row-major, 128x128 tile, 4 waves of 64x64
template <bool OUT_BF16>
__global__ __launch_bounds__(256) void gemm_bt(const bf16_t* __restrict__ A,
                                               const bf16_t* __restrict__ Bw,
                                               void* __restrict__ Cout,
                                               int M, int N, int K) {
    __shared__ bf16_t sA[128][72];
    __shared__ bf16_t sB[128][72];
    int tid = threadIdx.x;
    int lane = tid & 63, wid = tid >> 6;
    int m = lane & 15, quad = lane >> 4;
    int wm = (wid >> 1) * 64, wn = (wid & 1) * 64;
    int m0 = blockIdx.y * 128, n0 = blockIdx.x * 128;
    int r0 = tid >> 3, c8 = (tid & 7) << 3;

    f32x4 acc[4][4] = {};
    for (int k0 = 0; k0 < K; k0 += 64) {
        for (int p = 0; p < 4; ++p) {
            int row = r0 + p * 32;
            *(uint4*)&sA[row][c8] = *(const uint4*)&A[(size_t)(m0 + row) * K + k0 + c8];
            *(uint4*)&sB[row][c8] = *(const uint4*)&Bw[(size_t)(n0 + row) * K + k0 + c8];
        }
        __syncthreads();
        for (int ks = 0; ks < 64; ks += 32) {
            bf16x8 a[4], b[4];
            for (int i = 0; i < 4; ++i) a[i] = ldfrag(&sA[wm + i * 16 + m][ks + quad * 8]);
            for (int i = 0; i < 4; ++i) b[i] = ldfrag(&sB[wn + i * 16 + m][ks + quad * 8]);
            for (int i = 0; i < 4; ++i)
                for (int j = 0; j < 4; ++j)
                    acc[i][j] = __builtin_amdgcn_mfma_f32_16x16x32_bf16(a[i], b[j], acc[i][j], 0, 0, 0);
        }
        __syncthreads();
    }
    for (int i = 0; i < 4; ++i)
        for (int j = 0; j < 4; ++j)
            for (int r = 0; r < 4; ++r) {
                int row = m0 + wm + i * 16 + quad * 4 + r;
                int col = n0 + wn + j * 16 + m;
                float v = acc[i][j][r];
                if (OUT_BF16) ((bf16_t*)Cout)[(size_t)row * N + col] = (bf16_t)v;
                else          ((float*)Cout)[(size_t)row * N + col] = v;
            }
}

// V (qkv cols [2048 + h*64 .. +64)) -> Vt[bh][d][t], LDS 64x64 transpose
__global__ __launch_bounds__(256) void repack_vt(const bf16_t* __restrict__ qkv,
                                                 bf16_t* __restrict__ vt) {
    __shared__ bf16_t s[64][72];
    int t0 = (blockIdx.x & 31) << 6;
    int bh = blockIdx.x >> 5;
    int b = bh >> 4, h = bh & 15;
    int tid = threadIdx.x;
    int r = tid >> 3, c8 = (tid & 7) << 3;
    const bf16_t* src = qkv + (size_t)(b * T_SEQ) * C3 + 2048 + h * 64;
    for (int p = 0; p < 2; ++p) {
        int t = r + p * 32;
        *(uint4*)&s[t][c8] = *(const uint4*)&src[(size_t)(t0 + t) * C3 + c8];
    }
    __syncthreads();
    bf16_t* dst = vt + (size_t)bh * 64 * T_SEQ;
    for (int p = 0; p < 2; ++p) {
        int d = r + p * 32;
        bf16x8 vv;
        for (int i = 0; i < 8; ++i) vv[i] = s[c8 + i][d];
        *(bf16x8*)&dst[(size_t)d * T_SEQ + t0 + c8] = vv;
    }
}

// one block = one (b,h, 64-row tile). Two-pass softmax; writes attn (f32),
// y (bf16 context, [b*T+t][C]), atomicAdds energy partials into ews[0..1].
__global__ __launch_bounds__(256) void attn_kernel(const bf16_t* __restrict__ qkv,
                                                   const bf16_t* __restrict__ vt,
                                                   const float* __restrict__ dscales,
                                                   float* __restrict__ attn,
                                                   bf16_t* __restrict__ y,
                                                   float* __restrict__ ews) {
    __shared__ bf16_t sQ[64][72], sK[64][72], sV[64][72], sP[64][72];
    __shared__ float sred[8];
    // remap row-tile so each CU's resident blocks have ~constant total K-tiles
    int base = blockIdx.x & 31;
    int bh = (blockIdx.x >> 5) & 31;
    int it = (bh & 8) ? (31 - base) : base;
    int b = bh >> 4, h = bh & 15;
    int i0 = it << 6;
    int tid = threadIdx.x, lane = tid & 63, wid = tid >> 6;
    int m = lane & 15, quad = lane >> 4;
    int w16 = wid << 4;
    float dsc = dscales[h];
    const float scale = 0.125f;

    const bf16_t* Qb = qkv + (size_t)(b * T_SEQ) * C3 + h * 64;
    const bf16_t* Kb = Qb + 1024;
    const bf16_t* Vb = vt + (size_t)bh * 64 * T_SEQ;
    float* Ab = attn + ((size_t)bh * T_SEQ + i0) * T_SEQ;

    // causal upper-triangle zeros (d_out is poisoned every launch)
    {
        int zc0 = i0 + 64;
        for (int r = 0; r < 64; ++r) {
            float* rowp = Ab + (size_t)r * T_SEQ;
            for (int c = zc0 + (tid << 1); c < T_SEQ; c += 512)
                *(float2*)(rowp + c) = make_float2(0.f, 0.f);
        }
    }

    int r0 = tid >> 3, c8 = (tid & 7) << 3;
    for (int p = 0; p < 2; ++p) {
        int r = r0 + p * 32;
        *(uint4*)&sQ[r][c8] = *(const uint4*)&Qb[(size_t)(i0 + r) * C3 + c8];
    }

    float mrow[4], lrow[4];
    for (int r = 0; r < 4; ++r) { mrow[r] = -3.0e38f; lrow[r] = 0.f; }

    // ---- pass 1: row max + denominator ----
    for (int jt = 0; jt <= it; ++jt) {
        int j0 = jt << 6;
        __syncthreads();
        for (int p = 0; p < 2; ++p) {
            int rr = r0 + p * 32;
            *(uint4*)&sK[rr][c8] = *(const uint4*)&Kb[(size_t)(j0 + rr) * C3 + c8];
        }
        __syncthreads();
        f32x4 acc[4] = {};
        for (int ks = 0; ks < 64; ks += 32) {
            bf16x8 a = ldfrag(&sQ[w16 + m][ks + quad * 8]);
            for (int n = 0; n < 4; ++n) {
                bf16x8 bb = ldfrag(&sK[n * 16 + m][ks + quad * 8]);
                acc[n] = __builtin_amdgcn_mfma_f32_16x16x32_bf16(a, bb, acc[n], 0, 0, 0);
            }
        }
        for (int r = 0; r < 4; ++r) {
            int gi = i0 + w16 + quad * 4 + r;
            float s4[4];
            float mx = -3.0e38f;
            for (int n = 0; n < 4; ++n) {
                int gj = j0 + n * 16 + m;
                float s = acc[n][r] * scale - dsc * fabsf((float)(gi - gj));
                if (gj > gi) s = -3.0e38f;
                s4[n] = s;
                mx = fmaxf(mx, s);
            }
            for (int off = 1; off < 16; off <<= 1) mx = fmaxf(mx, __shfl_xor(mx, off));
            float mnew = fmaxf(mrow[r], mx);
            float se = 0.f;
            for (int n = 0; n < 4; ++n) se += __expf(s4[n] - mnew);
            for (int off = 1; off < 16; off <<= 1) se += __shfl_xor(se, off);
            lrow[r] = lrow[r] * __expf(mrow[r] - mnew) + se;
            mrow[r] = mnew;
        }
    }

    // ---- pass 2: write attn, accumulate energies, P@V ----
    float rl[4];
    for (int r = 0; r < 4; ++r) rl[r] = 1.f / lrow[r];
    f32x4 oacc[4] = {};
    float e_d = 0.f, e_e = 0.f;

    for (int jt = 0; jt <= it; ++jt) {
        int j0 = jt << 6;
        __syncthreads();
        for (int p = 0; p < 2; ++p) {
            int rr = r0 + p * 32;
            *(uint4*)&sK[rr][c8] = *(const uint4*)&Kb[(size_t)(j0 + rr) * C3 + c8];
            *(uint4*)&sV[rr][c8] = *(const uint4*)&Vb[(size_t)rr * T_SEQ + j0 + c8];
        }
        __syncthreads();
        f32x4 acc[4] = {};
        for (int ks = 0; ks < 64; ks += 32) {
            bf16x8 a = ldfrag(&sQ[w16 + m][ks + quad * 8]);
            for (int n = 0; n < 4; ++n) {
                bf16x8 bb = ldfrag(&sK[n * 16 + m][ks + quad * 8]);
                acc[n] = __builtin_amdgcn_mfma_f32_16x16x32_bf16(a, bb, acc[n], 0, 0, 0);
            }
        }
        for (int r = 0; r < 4; ++r) {
            int gi = i0 + w16 + quad * 4 + r;
            float* rowp = Ab + (size_t)(w16 + quad * 4 + r) * T_SEQ + j0;
            for (int n = 0; n < 4; ++n) {
                int gj = j0 + n * 16 + m;
                float d = fabsf((float)(gi - gj));
                float s = acc[n][r] * scale - dsc * d;
                if (gj > gi) s = -3.0e38f;
                float p = __expf(s - mrow[r]) * rl[r];
                rowp[n * 16 + m] = p;
                e_d += p * d;
                e_e += p * __logf(p + 1e-9f);
                sP[w16 + quad * 4 + r][n * 16 + m] = (bf16_t)p;
            }
        }
        __syncthreads();
        for (int ks = 0; ks < 64; ks += 32) {
            bf16x8 a = ldfrag(&sP[w16 + m][ks + quad * 8]);
            for (int n = 0; n < 4; ++n) {
                bf16x8 bb = ldfrag(&sV[n * 16 + m][ks + quad * 8]);
                oacc[n] = __builtin_amdgcn_mfma_f32_16x16x32_bf16(a, bb, oacc[n], 0, 0, 0);
            }
        }
    }

    for (int n = 0; n < 4; ++n)
        for (int r = 0; r < 4; ++r) {
            int t = i0 + w16 + quad * 4 + r;
            y[(size_t)(b * T_SEQ + t) * C_DIM + h * 64 + n * 16 + m] = (bf16_t)oacc[n][r];
        }

    for (int off = 1; off < 64; off <<= 1) {
        e_d += __shfl_xor(e_d, off);
        e_e += __shfl_xor(e_e, off);
    }
    if (lane == 0) { sred[wid] = e_d; sred[wid + 4] = e_e; }
    __syncthreads();
    if (tid == 0) {
        atomicAdd(ews, sred[0] + sred[1] + sred[2] + sred[3]);
        atomicAdd(ews + 1, sred[4] + sred[5] + sred[6] + sred[7]);
    }
}

__global__ void finalize_kernel(const float* __restrict__ ews, float* __restrict__ dout) {
    dout[4194304] = ews[0] / 65536.f;
    dout[4194305] = -ews[1] / 65536.f;
}

extern "C" void kernel_launch(void* const* d_in, const int* in_sizes, int n_in,
                              void* d_out, int out_size, void* d_ws, size_t ws_size,
                              hipStream_t stream) {
    const float* x = (const float*)d_in[0];
    const float* qkv_w = (const float*)d_in[1];
    const float* proj_w = (const float*)d_in[2];
    const float* dscales = (const float*)d_in[3];
    float* out = (float*)d_out;

    char* ws = (char*)d_ws;
    float* ews   = (float*)ws;                      // 2 floats (pad to 256B)
    bf16_t* xb   = (bf16_t*)(ws + 256);             // 4,194,304
    bf16_t* wb   = xb + 4194304;                    // 3,145,728
    bf16_t* pb   = wb + 3145728;                    // 1,048,576
    bf16_t* qkvb = pb + 1048576;                    // 12,582,912
    bf16_t* vtb  = qkvb + 12582912;                 // 4,194,304
    bf16_t* yb   = vtb + 4194304;                   // 4,194,304  (~58.8 MB total)

    cvt4_kernel<<<1024, 256, 0, stream>>>(x, xb, 4194304 / 4, ews);
    cvt4_kernel<<<1024, 256, 0, stream>>>(qkv_w, wb, 3145728 / 4, nullptr);
    cvt4_kernel<<<512, 256, 0, stream>>>(proj_w, pb, 1048576 / 4, nullptr);
    dists_kernel<<<16384, 256, 0, stream>>>(out + 138412034);

    gemm_bt<true><<<dim3(24, 32), 256, 0, stream>>>(xb, wb, qkvb, 4096, 3072, 1024);
    repack_vt<<<1024, 256, 0, stream>>>(qkvb, vtb);
    attn_kernel<<<1024, 256, 0, stream>>>(qkvb, vtb, dscales, out + 4194306, yb, ews);
    gemm_bt<false><<<dim3(8, 32), 256, 0, stream>>>(yb, pb, out, 4096, 1024, 1024);
    finalize_kernel<<<1, 1, 0, stream>>>(ews, out);
}

// Round 2
// 873.172 us; speedup vs baseline: 1.0485x; 1.0485x over previous
//
#include <hip/hip_runtime.h>
#include <hip/hip_bf16.h>
#include <math.h>

#define T_SEQ 2048
#define C3 3072
#define C_DIM 1024

typedef __bf16 bf16_t;
typedef __bf16 bf16x8 __attribute__((ext_vector_type(8)));
typedef __bf16 bf16x4_t __attribute__((ext_vector_type(4)));
typedef float f32x4 __attribute__((ext_vector_type(4)));

typedef __attribute__((address_space(1))) const void gconst_t;
typedef __attribute__((address_space(3))) void lds_t;

static __device__ __forceinline__ bf16x8 ldg8(const bf16_t* p) {
    return *reinterpret_cast<const bf16x8*>(p);
}

// f32 -> bf16, 4 elems/thread; first launch also zeroes the 2 energy accumulators
__global__ void cvt4_kernel(const float* __restrict__ in, bf16_t* __restrict__ out,
                            long n4, float* zbuf) {
    long i = (long)blockIdx.x * blockDim.x + threadIdx.x;
    if (zbuf && i < 2) zbuf[i] = 0.f;
    long stride = (long)gridDim.x * blockDim.x;
    for (; i < n4; i += stride) {
        float4 v = ((const float4*)in)[i];
        bf16x4_t o;
        o[0] = (bf16_t)v.x; o[1] = (bf16_t)v.y; o[2] = (bf16_t)v.z; o[3] = (bf16_t)v.w;
        *(bf16x4_t*)(out + i * 4) = o;
    }
}

__global__ void dists_kernel(float* __restrict__ dout) {
    int idx = blockIdx.x * 256 + threadIdx.x;
    int i = idx >> 11, j = idx & 2047;
    dout[idx] = (float)(i > j ? i - j : j - i);
}

// C = A @ B^T, A[M,K], B[N,K] bf16 row-major. BMx128 tile, global_load_lds
// width-16 staging with chunk^=(row&7) XOR swizzle (unpadded LDS, conflict-free
// ds_read_b128). MFMA operands swapped so each lane holds 4 consecutive C cols.
template <int BM, bool OUT_BF16>
__global__ __launch_bounds__(256) void gemm_bt(const bf16_t* __restrict__ A,
                                               const bf16_t* __restrict__ Bw,
                                               void* __restrict__ Cout,
                                               int M, int N, int K) {
    constexpr int WM = BM / 2;
    constexpr int MI = WM / 16;
    __shared__ bf16_t sA[BM * 64];
    __shared__ bf16_t sB[128 * 64];
    int tid = threadIdx.x, lane = tid & 63, wid = tid >> 6;
    int m = lane & 15, quad = lane >> 4;
    int wm = (wid >> 1) * WM, wn = (wid & 1) * 64;
    int m0 = blockIdx.y * BM, n0 = blockIdx.x * 128;
    int lrow = lane >> 3, cxor = (lane & 7) ^ (lrow & 7);

    const bf16_t* Ag = A + (size_t)(m0 + wid * 8 + lrow) * K + cxor * 8;
    const bf16_t* Bg = Bw + (size_t)(n0 + wid * 8 + lrow) * K + cxor * 8;

    f32x4 acc[MI][4] = {};
    for (int k0 = 0; k0 < K; k0 += 64) {
        for (int p = 0; p < BM / 32; ++p)
            __builtin_amdgcn_global_load_lds((gconst_t*)(Ag + (size_t)(p * 32) * K + k0),
                                             (lds_t*)(sA + (p * 32 + wid * 8) * 64), 16, 0, 0);
        for (int p = 0; p < 4; ++p)
            __builtin_amdgcn_global_load_lds((gconst_t*)(Bg + (size_t)(p * 32) * K + k0),
                                             (lds_t*)(sB + (p * 32 + wid * 8) * 64), 16, 0, 0);
        __syncthreads();
        for (int ks = 0; ks < 2; ++ks) {
            bf16x8 a[MI], b[4];
            for (int i = 0; i < MI; ++i) {
                int r = wm + i * 16 + m;
                a[i] = *(const bf16x8*)(sA + r * 64 + ((((ks << 2) + quad) ^ (r & 7)) << 3));
            }
            for (int j = 0; j < 4; ++j) {
                int r = wn + j * 16 + m;
                b[j] = *(const bf16x8*)(sB + r * 64 + ((((ks << 2) + quad) ^ (r & 7)) << 3));
            }
            for (int i = 0; i < MI; ++i)
                for (int j = 0; j < 4; ++j)
                    acc[i][j] = __builtin_amdgcn_mfma_f32_16x16x32_bf16(b[j], a[i], acc[i][j], 0, 0, 0);
        }
        __syncthreads();
    }
    for (int i = 0; i < MI; ++i)
        for (int j = 0; j < 4; ++j) {
            size_t row = m0 + wm + i * 16 + m;
            int col = n0 + wn + j * 16 + quad * 4;
            if (OUT_BF16) {
                bf16x4_t o;
                for (int r = 0; r < 4; ++r) o[r] = (bf16_t)acc[i][j][r];
                *(bf16x4_t*)((bf16_t*)Cout + row * N + col) = o;
            } else {
                *(f32x4*)((float*)Cout + row * N + col) = acc[i][j];
            }
        }
}

// V (qkv cols [2048 + h*64 .. +64)) -> Vt[bh][d][t], LDS 64x64 transpose
__global__ __launch_bounds__(256) void repack_vt(const bf16_t* __restrict__ qkv,
                                                 bf16_t* __restrict__ vt) {
    __shared__ bf16_t s[64][72];
    int t0 = (blockIdx.x & 31) << 6;
    int bh = blockIdx.x >> 5;
    int b = bh >> 4, h = bh & 15;
    int tid = threadIdx.x;
    int r = tid >> 3, c8 = (tid & 7) << 3;
    const bf16_t* src = qkv + (size_t)(b * T_SEQ) * C3 + 2048 + h * 64;
    for (int p = 0; p < 2; ++p) {
        int t = r + p * 32;
        *(uint4*)&s[t][c8] = *(const uint4*)&src[(size_t)(t0 + t) * C3 + c8];
    }
    __syncthreads();
    bf16_t* dst = vt + (size_t)bh * 64 * T_SEQ;
    for (int p = 0; p < 2; ++p) {
        int d = r + p * 32;
        bf16x8 vv;
        for (int i = 0; i < 8; ++i) vv[i] = s[c8 + i][d];
        *(bf16x8*)&dst[(size_t)d * T_SEQ + t0 + c8] = vv;
    }
}

// one block = one (b,h, 64-row tile). Swapped-operand MFMA: each lane owns one
// fixed attn row i = w16 + (lane&15). Pass 1 (barrier-free, no LDS): row sums
// of exp(s) — no max needed, |s_qk| <= 8 bound. Pass 2: float4 attn stores,
// energies, P@V via sP round-trip. Far tiles (exp underflow) skipped/zeroed.
__global__ __launch_bounds__(256) void attn_kernel(const bf16_t* __restrict__ qkv,
                                                   const bf16_t* __restrict__ vt,
                                                   const float* __restrict__ dscales,
                                                   float* __restrict__ attn,
                                                   bf16_t* __restrict__ y,
                                                   float* __restrict__ ews) {
    __shared__ bf16_t sP[64][72];
    __shared__ float sred[8];
    // remap row-tile so each CU's resident blocks have ~constant total work
    int base = blockIdx.x & 31;
    int bh = blockIdx.x >> 5;
    int it = (bh & 8) ? (31 - base) : base;
    int b = bh >> 4, h = bh & 15;
    int i0 = it << 6;
    int tid = threadIdx.x, lane = tid & 63, wid = tid >> 6;
    int m = lane & 15, quad = lane >> 4;
    int w16 = wid << 4;
    float dsc = dscales[h];
    const float scale = 0.125f;
    const float zthr = 111.0f;  // exp-underflow margin vs |s_qk|<=8

    const bf16_t* Qb = qkv + (size_t)(b * T_SEQ) * C3 + h * 64;
    const bf16_t* Kb = Qb + 1024;
    const bf16_t* Vb = vt + (size_t)bh * 64 * T_SEQ;
    float* Ab = attn + ((size_t)bh * T_SEQ + i0) * T_SEQ;

    // causal upper-triangle zeros beyond the diagonal tile (d_out is poisoned)
    {
        int zc0 = i0 + 64, zn = T_SEQ - zc0;
        f32x4 z4 = {0.f, 0.f, 0.f, 0.f};
        for (int r = 0; r < 64; ++r) {
            float* rowp = Ab + (size_t)r * T_SEQ + zc0;
            for (int c = tid << 2; c < zn; c += 1024)
                *(f32x4*)(rowp + c) = z4;
        }
    }

    int i = i0 + w16 + m;  // this lane's fixed attn row
    bf16x8 qf[2];
    qf[0] = ldg8(Qb + (size_t)i * C3 + quad * 8);
    qf[1] = ldg8(Qb + (size_t)i * C3 + 32 + quad * 8);

    // ---- pass 1: row denominators (no barriers, no LDS) ----
    float lsum = 0.f;
    for (int jt = 0; jt <= it; ++jt) {
        int j0 = jt << 6;
        if ((float)(i0 - j0 - 63) * dsc > zthr) continue;
        f32x4 acc[4] = {};
        for (int ks = 0; ks < 2; ++ks)
            for (int n = 0; n < 4; ++n) {
                bf16x8 kf = ldg8(Kb + (size_t)(j0 + n * 16 + m) * C3 + ks * 32 + quad * 8);
                acc[n] = __builtin_amdgcn_mfma_f32_16x16x32_bf16(kf, qf[ks], acc[n], 0, 0, 0);
            }
        if (jt < it) {
            for (int n = 0; n < 4; ++n)
                for (int r = 0; r < 4; ++r) {
                    float d = (float)(i - (j0 + n * 16 + quad * 4 + r));
                    lsum += __expf(acc[n][r] * scale - dsc * d);
                }
        } else {
            for (int n = 0; n < 4; ++n)
                for (int r = 0; r < 4; ++r) {
                    int j = j0 + n * 16 + quad * 4 + r;
                    if (j <= i) lsum += __expf(acc[n][r] * scale - dsc * (float)(i - j));
                }
        }
    }
    lsum += __shfl_xor(lsum, 16);
    lsum += __shfl_xor(lsum, 32);
    float rl = 1.f / lsum;

    // ---- pass 2: write attn (float4), energies, P@V ----
    f32x4 oacc[4] = {};
    float e_d = 0.f, e_e = 0.f;

    for (int jt = 0; jt <= it; ++jt) {
        int j0 = jt << 6;
        if ((float)(i0 - j0 - 63) * dsc > zthr) {
            int rr = tid >> 2, c0 = (tid & 3) << 4;
            float* p0 = Ab + (size_t)rr * T_SEQ + j0 + c0;
            f32x4 z4 = {0.f, 0.f, 0.f, 0.f};
            for (int u = 0; u < 4; ++u) *(f32x4*)(p0 + u * 4) = z4;
            continue;
        }
        f32x4 acc[4] = {};
        for (int ks = 0; ks < 2; ++ks)
            for (int n = 0; n < 4; ++n) {
                bf16x8 kf = ldg8(Kb + (size_t)(j0 + n * 16 + m) * C3 + ks * 32 + quad * 8);
                acc[n] = __builtin_amdgcn_mfma_f32_16x16x32_bf16(kf, qf[ks], acc[n], 0, 0, 0);
            }
        __syncthreads();  // prior tile's sP reads complete
        bool diag = (jt == it);
        for (int n = 0; n < 4; ++n) {
            f32x4 pv;
            for (int r = 0; r < 4; ++r) {
                int j = j0 + n * 16 + quad * 4 + r;
                float p = 0.f;
                if (!diag || j <= i) {
                    float d = (float)(i - j);
                    p = __expf(acc[n][r] * scale - dsc * d) * rl;
                    e_d += p * d;
                    e_e += p * __logf(p + 1e-9f);
                }
                pv[r] = p;
            }
            *(f32x4*)(Ab + (size_t)(w16 + m) * T_SEQ + j0 + n * 16 + quad * 4) = pv;
            bf16x4_t pb;
            for (int r = 0; r < 4; ++r) pb[r] = (bf16_t)pv[r];
            *(bf16x4_t*)&sP[w16 + m][n * 16 + quad * 4] = pb;
        }
        __syncthreads();
        for (int ks = 0; ks < 2; ++ks) {
            bf16x8 pf = *(const bf16x8*)&sP[w16 + m][ks * 32 + quad * 8];
            for (int n = 0; n < 4; ++n) {
                bf16x8 vf = ldg8(Vb + (size_t)(n * 16 + m) * T_SEQ + j0 + ks * 32 + quad * 8);
                oacc[n] = __builtin_amdgcn_mfma_f32_16x16x32_bf16(vf, pf, oacc[n], 0, 0, 0);
            }
        }
    }

    // oacc[n]: rows d = n*16+quad*4+r, col i  -> y[i][h*64+d], bf16x4 stores
    for (int n = 0; n < 4; ++n) {
        bf16x4_t o;
        for (int r = 0; r < 4; ++r) o[r] = (bf16_t)oacc[n][r];
        *(bf16x4_t*)(y + (size_t)(b * T_SEQ + i) * C_DIM + h * 64 + n * 16 + quad * 4) = o;
    }

    for (int off = 1; off < 64; off <<= 1) {
        e_d += __shfl_xor(e_d, off);
        e_e += __shfl_xor(e_e, off);
    }
    if (lane == 0) { sred[wid] = e_d; sred[wid + 4] = e_e; }
    __syncthreads();
    if (tid == 0) {
        atomicAdd(ews, sred[0] + sred[1] + sred[2] + sred[3]);
        atomicAdd(ews + 1, sred[4] + sred[5] + sred[6] + sred[7]);
    }
}

__global__ void finalize_kernel(const float* __restrict__ ews, float* __restrict__ dout) {
    dout[4194304] = ews[0] / 65536.f;
    dout[4194305] = -ews[1] / 65536.f;
}

extern "C" void kernel_launch(void* const* d_in, const int* in_sizes, int n_in,
                              void* d_out, int out_size, void* d_ws, size_t ws_size,
                              hipStream_t stream) {
    const float* x = (const float*)d_in[0];
    const float* qkv_w = (const float*)d_in[1];
    const float* proj_w = (const float*)d_in[2];
    const float* dscales = (const float*)d_in[3];
    float* out = (float*)d_out;

    char* ws = (char*)d_ws;
    float* ews   = (float*)ws;                      // 2 floats (pad to 256B)
    bf16_t* xb   = (bf16_t*)(ws + 256);             // 4,194,304
    bf16_t* wb   = xb + 4194304;                    // 3,145,728
    bf16_t* pb   = wb + 3145728;                    // 1,048,576
    bf16_t* qkvb = pb + 1048576;                    // 12,582,912
    bf16_t* vtb  = qkvb + 12582912;                 // 4,194,304
    bf16_t* yb   = vtb + 4194304;                   // 4,194,304  (~58.8 MB total)

    cvt4_kernel<<<1024, 256, 0, stream>>>(x, xb, 4194304 / 4, ews);
    cvt4_kernel<<<1024, 256, 0, stream>>>(qkv_w, wb, 3145728 / 4, nullptr);
    cvt4_kernel<<<512, 256, 0, stream>>>(proj_w, pb, 1048576 / 4, nullptr);
    dists_kernel<<<16384, 256, 0, stream>>>(out + 138412034);

    gemm_bt<128, true><<<dim3(24, 32), 256, 0, stream>>>(xb, wb, qkvb, 4096, 3072, 1024);
    repack_vt<<<1024, 256, 0, stream>>>(qkvb, vtb);
    attn_kernel<<<1024, 256, 0, stream>>>(qkvb, vtb, dscales, out + 4194306, yb, ews);
    gemm_bt<64, false><<<dim3(8, 64), 256, 0, stream>>>(yb, pb, out, 4096, 1024, 1024);
    finalize_kernel<<<1, 1, 0, stream>>>(ews, out);
}

// Round 3
// 850.449 us; speedup vs baseline: 1.0765x; 1.0267x over previous
//
#include <hip/hip_runtime.h>
#include <hip/hip_bf16.h>
#include <math.h>

#define T_SEQ 2048
#define C3 3072
#define C_DIM 1024

typedef __bf16 bf16_t;
typedef __bf16 bf16x8 __attribute__((ext_vector_type(8)));
typedef __bf16 bf16x4_t __attribute__((ext_vector_type(4)));
typedef float f32x4 __attribute__((ext_vector_type(4)));

typedef __attribute__((address_space(1))) const void gconst_t;
typedef __attribute__((address_space(3))) void lds_t;

static __device__ __forceinline__ bf16x8 ldg8(const bf16_t* p) {
    return *reinterpret_cast<const bf16x8*>(p);
}

// One launch: f32->bf16 casts of x/qkv_w/proj_w, dists output, ews zeroing.
// Unit = one float4 (cvt) or one f32x4 of dists. 3,145,728 units total.
__global__ __launch_bounds__(256) void aux_kernel(const float* __restrict__ x,
                                                  const float* __restrict__ qw,
                                                  const float* __restrict__ pw,
                                                  bf16_t* __restrict__ xb,
                                                  bf16_t* __restrict__ wb,
                                                  bf16_t* __restrict__ pb,
                                                  float* __restrict__ dout,
                                                  float* __restrict__ ews) {
    long gid = (long)blockIdx.x * 256 + threadIdx.x;
    if (gid < 2) ews[gid] = 0.f;
    const float* src;
    bf16_t* dst;
    long u;
    if (gid < 1048576) { src = x; dst = xb; u = gid; }
    else if (gid < 1835008) { src = qw; dst = wb; u = gid - 1048576; }
    else if (gid < 2097152) { src = pw; dst = pb; u = gid - 1835008; }
    else {
        long v = gid - 2097152;           // dists: 4 consecutive cols of one row
        long e0 = v << 2;
        int i = (int)(e0 >> 11), j0 = (int)(e0 & 2047);
        f32x4 o;
        for (int r = 0; r < 4; ++r) {
            int j = j0 + r;
            o[r] = (float)(i > j ? i - j : j - i);
        }
        __builtin_nontemporal_store(o, (f32x4*)(dout + e0));
        return;
    }
    float4 v4 = ((const float4*)src)[u];
    bf16x4_t o;
    o[0] = (bf16_t)v4.x; o[1] = (bf16_t)v4.y; o[2] = (bf16_t)v4.z; o[3] = (bf16_t)v4.w;
    *(bf16x4_t*)(dst + u * 4) = o;
}

// C = A @ B^T, A[M,K], B[N,K] bf16 row-major. BMx128 tile, global_load_lds
// width-16 staging with chunk^=(row&7) XOR swizzle (unpadded LDS, conflict-free
// ds_read_b128). MFMA operands swapped so each lane holds 4 consecutive C cols.
template <int BM, bool OUT_BF16>
__global__ __launch_bounds__(256) void gemm_bt(const bf16_t* __restrict__ A,
                                               const bf16_t* __restrict__ Bw,
                                               void* __restrict__ Cout,
                                               int M, int N, int K) {
    constexpr int WM = BM / 2;
    constexpr int MI = WM / 16;
    __shared__ bf16_t sA[BM * 64];
    __shared__ bf16_t sB[128 * 64];
    int tid = threadIdx.x, lane = tid & 63, wid = tid >> 6;
    int m = lane & 15, quad = lane >> 4;
    int wm = (wid >> 1) * WM, wn = (wid & 1) * 64;
    int m0 = blockIdx.y * BM, n0 = blockIdx.x * 128;
    int lrow = lane >> 3, cxor = (lane & 7) ^ (lrow & 7);

    const bf16_t* Ag = A + (size_t)(m0 + wid * 8 + lrow) * K + cxor * 8;
    const bf16_t* Bg = Bw + (size_t)(n0 + wid * 8 + lrow) * K + cxor * 8;

    f32x4 acc[MI][4] = {};
    for (int k0 = 0; k0 < K; k0 += 64) {
        for (int p = 0; p < BM / 32; ++p)
            __builtin_amdgcn_global_load_lds((gconst_t*)(Ag + (size_t)(p * 32) * K + k0),
                                             (lds_t*)(sA + (p * 32 + wid * 8) * 64), 16, 0, 0);
        for (int p = 0; p < 4; ++p)
            __builtin_amdgcn_global_load_lds((gconst_t*)(Bg + (size_t)(p * 32) * K + k0),
                                             (lds_t*)(sB + (p * 32 + wid * 8) * 64), 16, 0, 0);
        __syncthreads();
        for (int ks = 0; ks < 2; ++ks) {
            bf16x8 a[MI], b[4];
            for (int i = 0; i < MI; ++i) {
                int r = wm + i * 16 + m;
                a[i] = *(const bf16x8*)(sA + r * 64 + ((((ks << 2) + quad) ^ (r & 7)) << 3));
            }
            for (int j = 0; j < 4; ++j) {
                int r = wn + j * 16 + m;
                b[j] = *(const bf16x8*)(sB + r * 64 + ((((ks << 2) + quad) ^ (r & 7)) << 3));
            }
            for (int i = 0; i < MI; ++i)
                for (int j = 0; j < 4; ++j)
                    acc[i][j] = __builtin_amdgcn_mfma_f32_16x16x32_bf16(b[j], a[i], acc[i][j], 0, 0, 0);
        }
        __syncthreads();
    }
    for (int i = 0; i < MI; ++i)
        for (int j = 0; j < 4; ++j) {
            size_t row = m0 + wm + i * 16 + m;
            int col = n0 + wn + j * 16 + quad * 4;
            if (OUT_BF16) {
                bf16x4_t o;
                for (int r = 0; r < 4; ++r) o[r] = (bf16_t)acc[i][j][r];
                *(bf16x4_t*)((bf16_t*)Cout + row * N + col) = o;
            } else {
                *(f32x4*)((float*)Cout + row * N + col) = acc[i][j];
            }
        }
}

// V (qkv cols [2048 + h*64 .. +64)) -> Vt[bh][d][t], LDS 64x64 transpose
__global__ __launch_bounds__(256) void repack_vt(const bf16_t* __restrict__ qkv,
                                                 bf16_t* __restrict__ vt) {
    __shared__ bf16_t s[64][72];
    int t0 = (blockIdx.x & 31) << 6;
    int bh = blockIdx.x >> 5;
    int b = bh >> 4, h = bh & 15;
    int tid = threadIdx.x;
    int r = tid >> 3, c8 = (tid & 7) << 3;
    const bf16_t* src = qkv + (size_t)(b * T_SEQ) * C3 + 2048 + h * 64;
    for (int p = 0; p < 2; ++p) {
        int t = r + p * 32;
        *(uint4*)&s[t][c8] = *(const uint4*)&src[(size_t)(t0 + t) * C3 + c8];
    }
    __syncthreads();
    bf16_t* dst = vt + (size_t)bh * 64 * T_SEQ;
    for (int p = 0; p < 2; ++p) {
        int d = r + p * 32;
        bf16x8 vv;
        for (int i = 0; i < 8; ++i) vv[i] = s[c8 + i][d];
        *(bf16x8*)&dst[(size_t)d * T_SEQ + t0 + c8] = vv;
    }
}

// one block = one (b,h, 64-row tile). Each lane owns one fixed attn row
// i = w16 + (lane&15) (swapped-operand MFMA). Pass 1 (barrier-free, no LDS):
// row denominators — no max needed, |s_qk| <= 8 bound. Pass 2: nt float4 attn
// stores, energies via  sum p*ln p = sum p*v - ln(lsum)  (no per-entry log),
// P@V via sP round-trip. Tiles with distance penalty > 38 (p <= ~1e-12)
// are skipped and zero-filled.
__global__ __launch_bounds__(256) void attn_kernel(const bf16_t* __restrict__ qkv,
                                                   const bf16_t* __restrict__ vt,
                                                   const float* __restrict__ dscales,
                                                   float* __restrict__ attn,
                                                   bf16_t* __restrict__ y,
                                                   float* __restrict__ ews) {
    __shared__ bf16_t sP[64][72];
    __shared__ float sred[8];
    // remap: blocks i and i+256 (same CU under round-robin) get it summing 31
    int base = blockIdx.x & 31;
    int bh = blockIdx.x >> 5;
    int it = (bh & 8) ? (31 - base) : base;
    int b = bh >> 4, h = bh & 15;
    int i0 = it << 6;
    int tid = threadIdx.x, lane = tid & 63, wid = tid >> 6;
    int m = lane & 15, quad = lane >> 4;
    int w16 = wid << 4;
    float dsc = dscales[h];
    const float scale = 0.125f;

    // negligible-tile cutoff: skip jt with (it-jt)*64-63 > 38/dsc
    int jskip = 0;
    if (dsc > 1e-6f) {
        int keep = (int)(38.0f / dsc + 63.0f) >> 6;
        jskip = it - keep;
        if (jskip < 0) jskip = 0;
    }

    const bf16_t* Qb = qkv + (size_t)(b * T_SEQ) * C3 + h * 64;
    const bf16_t* Kb = Qb + 1024;
    const bf16_t* Vb = vt + (size_t)bh * 64 * T_SEQ;
    float* Ab = attn + ((size_t)bh * T_SEQ + i0) * T_SEQ;

    // zero fills: left skipped rect [0, jskip*64), causal rect [i0+64, 2048)
    {
        f32x4 z4 = {0.f, 0.f, 0.f, 0.f};
        int ln = jskip << 6;
        for (int r = 0; r < 64; ++r) {
            float* rowp = Ab + (size_t)r * T_SEQ;
            for (int c = tid << 2; c < ln; c += 1024)
                __builtin_nontemporal_store(z4, (f32x4*)(rowp + c));
        }
        int zc0 = i0 + 64, zn = T_SEQ - zc0;
        for (int r = 0; r < 64; ++r) {
            float* rowp = Ab + (size_t)r * T_SEQ + zc0;
            for (int c = tid << 2; c < zn; c += 1024)
                __builtin_nontemporal_store(z4, (f32x4*)(rowp + c));
        }
    }

    int i = i0 + w16 + m;  // this lane's fixed attn row
    bf16x8 qf[2];
    qf[0] = ldg8(Qb + (size_t)i * C3 + quad * 8);
    qf[1] = ldg8(Qb + (size_t)i * C3 + 32 + quad * 8);

    // ---- pass 1: row denominators (no barriers, no LDS) ----
    float lsum = 0.f;
    for (int jt = jskip; jt <= it; ++jt) {
        int j0 = jt << 6;
        f32x4 acc[4] = {};
        for (int ks = 0; ks < 2; ++ks)
            for (int n = 0; n < 4; ++n) {
                bf16x8 kf = ldg8(Kb + (size_t)(j0 + n * 16 + m) * C3 + ks * 32 + quad * 8);
                acc[n] = __builtin_amdgcn_mfma_f32_16x16x32_bf16(kf, qf[ks], acc[n], 0, 0, 0);
            }
        if (jt < it) {
            for (int n = 0; n < 4; ++n)
                for (int r = 0; r < 4; ++r) {
                    float d = (float)(i - (j0 + n * 16 + quad * 4 + r));
                    lsum += __expf(acc[n][r] * scale - dsc * d);
                }
        } else {
            for (int n = 0; n < 4; ++n)
                for (int r = 0; r < 4; ++r) {
                    int j = j0 + n * 16 + quad * 4 + r;
                    if (j <= i) lsum += __expf(acc[n][r] * scale - dsc * (float)(i - j));
                }
        }
    }
    lsum += __shfl_xor(lsum, 16);
    lsum += __shfl_xor(lsum, 32);
    float rl = 1.f / lsum;

    // ---- pass 2: write attn (nt float4), energies, P@V ----
    f32x4 oacc[4] = {};
    float e_d = 0.f;
    float e_e = (quad == 0) ? -__logf(lsum) : 0.f;  // per-row ln(rl), once

    for (int jt = jskip; jt <= it; ++jt) {
        int j0 = jt << 6;
        f32x4 acc[4] = {};
        for (int ks = 0; ks < 2; ++ks)
            for (int n = 0; n < 4; ++n) {
                bf16x8 kf = ldg8(Kb + (size_t)(j0 + n * 16 + m) * C3 + ks * 32 + quad * 8);
                acc[n] = __builtin_amdgcn_mfma_f32_16x16x32_bf16(kf, qf[ks], acc[n], 0, 0, 0);
            }
        __syncthreads();  // prior tile's sP reads complete
        bool diag = (jt == it);
        for (int n = 0; n < 4; ++n) {
            f32x4 pv;
            for (int r = 0; r < 4; ++r) {
                int j = j0 + n * 16 + quad * 4 + r;
                float p = 0.f;
                if (!diag || j <= i) {
                    float d = (float)(i - j);
                    float v = acc[n][r] * scale - dsc * d;
                    p = __expf(v) * rl;
                    e_d += p * d;
                    e_e += p * v;   // sum p*v; + ln(rl) added once per row
                }
                pv[r] = p;
            }
            __builtin_nontemporal_store(
                pv, (f32x4*)(Ab + (size_t)(w16 + m) * T_SEQ + j0 + n * 16 + quad * 4));
            bf16x4_t pb;
            for (int r = 0; r < 4; ++r) pb[r] = (bf16_t)pv[r];
            *(bf16x4_t*)&sP[w16 + m][n * 16 + quad * 4] = pb;
        }
        __syncthreads();
        for (int ks = 0; ks < 2; ++ks) {
            bf16x8 pf = *(const bf16x8*)&sP[w16 + m][ks * 32 + quad * 8];
            for (int n = 0; n < 4; ++n) {
                bf16x8 vf = ldg8(Vb + (size_t)(n * 16 + m) * T_SEQ + j0 + ks * 32 + quad * 8);
                oacc[n] = __builtin_amdgcn_mfma_f32_16x16x32_bf16(vf, pf, oacc[n], 0, 0, 0);
            }
        }
    }

    // oacc[n]: rows d = n*16+quad*4+r, col i  -> y[i][h*64+d], bf16x4 stores
    for (int n = 0; n < 4; ++n) {
        bf16x4_t o;
        for (int r = 0; r < 4; ++r) o[r] = (bf16_t)oacc[n][r];
        *(bf16x4_t*)(y + (size_t)(b * T_SEQ + i) * C_DIM + h * 64 + n * 16 + quad * 4) = o;
    }

    for (int off = 1; off < 64; off <<= 1) {
        e_d += __shfl_xor(e_d, off);
        e_e += __shfl_xor(e_e, off);
    }
    if (lane == 0) { sred[wid] = e_d; sred[wid + 4] = e_e; }
    __syncthreads();
    if (tid == 0) {
        atomicAdd(ews, sred[0] + sred[1] + sred[2] + sred[3]);
        atomicAdd(ews + 1, sred[4] + sred[5] + sred[6] + sred[7]);
    }
}

__global__ void finalize_kernel(const float* __restrict__ ews, float* __restrict__ dout) {
    dout[4194304] = ews[0] / 65536.f;
    dout[4194305] = -ews[1] / 65536.f;
}

extern "C" void kernel_launch(void* const* d_in, const int* in_sizes, int n_in,
                              void* d_out, int out_size, void* d_ws, size_t ws_size,
                              hipStream_t stream) {
    const float* x = (const float*)d_in[0];
    const float* qkv_w = (const float*)d_in[1];
    const float* proj_w = (const float*)d_in[2];
    const float* dscales = (const float*)d_in[3];
    float* out = (float*)d_out;

    char* ws = (char*)d_ws;
    float* ews   = (float*)ws;                      // 2 floats (pad to 256B)
    bf16_t* xb   = (bf16_t*)(ws + 256);             // 4,194,304
    bf16_t* wb   = xb + 4194304;                    // 3,145,728
    bf16_t* pb   = wb + 3145728;                    // 1,048,576
    bf16_t* qkvb = pb + 1048576;                    // 12,582,912
    bf16_t* vtb  = qkvb + 12582912;                 // 4,194,304
    bf16_t* yb   = vtb + 4194304;                   // 4,194,304  (~58.8 MB total)

    aux_kernel<<<12288, 256, 0, stream>>>(x, qkv_w, proj_w, xb, wb, pb,
                                          out + 138412034, ews);
    gemm_bt<128, true><<<dim3(24, 32), 256, 0, stream>>>(xb, wb, qkvb, 4096, 3072, 1024);
    repack_vt<<<1024, 256, 0, stream>>>(qkvb, vtb);
    attn_kernel<<<1024, 256, 0, stream>>>(qkvb, vtb, dscales, out + 4194306, yb, ews);
    gemm_bt<64, false><<<dim3(8, 64), 256, 0, stream>>>(yb, pb, out, 4096, 1024, 1024);
    finalize_kernel<<<1, 1, 0, stream>>>(ews, out);
}